// Round 1
// baseline (218.010 us; speedup 1.0000x reference)
//
#include <hip/hip_runtime.h>

// FWHT over last dim (n = 4096), normalized by 1/64. One block (256 thr) per row.
// 12 butterfly bits in 3 register phases (butterflies commute, any order works):
//   P1: bits {0,1,10,11}  (from float4 global load: e=bits0..1, reg j=bits10..11)
//   P2: bits {2..5}       (LDS exchange, scalar b32, 2-way banks max = free)
//   P3: bits {6..9}       (LDS exchange)
// Final gather pass: P3 writes back to LDS, then conflict-free ds_read_b128 +
// nontemporal global_store_dwordx4 (was 16 scalar dword stores/thread).
// All LDS addresses use the involutive XOR swizzle S(A) = A ^ (((A>>6)&7)<<2)
// (fixed bijection on dword addrs -> correctness-neutral). Verified bank math:
//   P1 write / gather read: b128 at float4 idx (t ^ ((t>>4)&7)) + 256j -> per-16-lane
//     permutation of canonical pattern -> conflict-free.
//   P2 r/w: bank = (t&3) + 4*((r&7)^((t>>2)&7)) -> 32 distinct banks per half-wave,
//     2-way across halves -> free (m136).
//   P3 r/w: physical bank = l&31 -> 2-way -> free.

using v4 = __attribute__((ext_vector_type(4))) float;

__device__ __forceinline__ void had16(float x[16]) {
#pragma unroll
    for (int h = 1; h < 16; h <<= 1) {
#pragma unroll
        for (int i = 0; i < 16; ++i) {
            if (!(i & h)) {
                float a = x[i], b = x[i ^ h];
                x[i] = a + b; x[i ^ h] = a - b;
            }
        }
    }
}

__global__ void __launch_bounds__(256) fwht4096_kernel(const float* __restrict__ in,
                                                       float* __restrict__ out) {
    __shared__ float lds[4096];
    const int t = threadIdx.x;
    const size_t base = (size_t)blockIdx.x * 4096;
    const v4* in4 = reinterpret_cast<const v4*>(in + base);
    v4* out4 = reinterpret_cast<v4*>(out + base);

    // ---------------- P1: bits {0,1,10,11} ----------------
    v4 v[4];
#pragma unroll
    for (int j = 0; j < 4; ++j) v[j] = __builtin_nontemporal_load(&in4[t + 256 * j]);

#pragma unroll
    for (int j = 0; j < 4; ++j) {  // bits 0,1 (within float4)
        float a = v[j][0], b = v[j][1], c = v[j][2], d = v[j][3];
        float ab = a + b, amb = a - b, cd = c + d, cmd = c - d;
        v[j][0] = ab + cd; v[j][1] = amb + cmd; v[j][2] = ab - cd; v[j][3] = amb - cmd;
    }
    {  // bits 10,11 (across j)
        v4 s0 = v[0] + v[1], d0 = v[0] - v[1];
        v4 s1 = v[2] + v[3], d1 = v[2] - v[3];
        v[0] = s0 + s1; v[2] = s0 - s1;
        v[1] = d0 + d1; v[3] = d0 - d1;
    }
    {  // LDS write at S(4t + 1024j): float4 idx (t ^ ((t>>4)&7)) + 256j
        v4* l4 = reinterpret_cast<v4*>(lds);
        const int wb = t ^ ((t >> 4) & 7);
#pragma unroll
        for (int j = 0; j < 4; ++j) l4[wb + 256 * j] = v[j];
    }
    __syncthreads();

    float x[16];

    // ---------------- P2: bits {2..5} ----------------
    // logical elem = (t&3) + 4r + 64*(t>>2); physical = logical with r ^= s2
    {
        const int b2 = (t & 3) + 64 * (t >> 2);
        const int s2 = (t >> 2) & 7;
#pragma unroll
        for (int r = 0; r < 16; ++r) x[r] = lds[b2 + 4 * (r ^ s2)];
        had16(x);
#pragma unroll
        for (int r = 0; r < 16; ++r) lds[b2 + 4 * (r ^ s2)] = x[r];
    }
    __syncthreads();

    // ---------------- P3: bits {6..9} ----------------
    // logical elem = l + 64r + 1024w; physical low-6 = l ^ ((r&7)<<2)
    {
        const int l = t & 63, w = t >> 6;
        const int b3 = 1024 * w;
#pragma unroll
        for (int r = 0; r < 16; ++r) x[r] = lds[(l ^ ((r & 7) << 2)) + 64 * r + b3];
        had16(x);
        const float scale = 0.015625f;  // 1/64 = 1/sqrt(4096), exact
#pragma unroll
        for (int r = 0; r < 16; ++r) lds[(l ^ ((r & 7) << 2)) + 64 * r + b3] = x[r] * scale;
    }
    __syncthreads();

    // ---------------- Gather + vectorized nontemporal store ----------------
    {
        const v4* l4 = reinterpret_cast<const v4*>(lds);
        const int wb = t ^ ((t >> 4) & 7);
#pragma unroll
        for (int j = 0; j < 4; ++j) {
            v4 o = l4[wb + 256 * j];
            __builtin_nontemporal_store(o, &out4[t + 256 * j]);
        }
    }
}

extern "C" void kernel_launch(void* const* d_in, const int* in_sizes, int n_in,
                              void* d_out, int out_size, void* d_ws, size_t ws_size,
                              hipStream_t stream) {
    const float* x = (const float*)d_in[0];
    float* out = (float*)d_out;
    const int rows = in_sizes[0] >> 12;  // / 4096
    fwht4096_kernel<<<dim3(rows), dim3(256), 0, stream>>>(x, out);
}

// Round 3
// 217.774 us; speedup vs baseline: 1.0011x; 1.0011x over previous
//
#include <hip/hip_runtime.h>

// FWHT over last dim (n = 4096), normalized by 1/64. One block (256 thr) per row.
// 12 butterfly bits in 3 phases with only TWO LDS round-trips:
//   P1 (regs): bits {0,1}  (float4 components)
//              bits {10,11} (across j = 4 loaded float4s)
//              bits {6,7}   (v_permlane16/32_swap_b32 BUILTINS — element bit6 =
//                            lane bit4, bit7 = lane bit5; VALU pipe, no LDS traffic.
//                            R2 post-mortem: raw inline-asm version failed (absmax
//                            7.16) — VALU->permlane wait-state hazard invisible to
//                            the compiler inside an asm string. Builtins let the
//                            hazard recognizer see the opcode.)
//   P2 (LDS):  bits {2..5}  (scalar b32 exchange, conflict-free swizzle)
//   P3 (LDS):  bits {8,9}   (b128 gather of 4 float4s at f4idx l+64m+256w,
//                            butterfly across m in regs, scale, direct nt-store)
// LDS ops/thread: 4 b128 W + 16 b32 R + 16 b32 W + 4 b128 R = 40 (was 72 in R1).
// All LDS addresses use the involutive XOR swizzle on float4 idx: F ^= (F>>4)&7.
// Bank math (SQ_LDS_BANK_CONFLICT == 0 verified for this swizzle family in R1):
//   P1 write at wb = t ^ ((t>>4)&7) + 256j: per-16-lane group the XOR term is
//     constant -> residues mod 8 each hit exactly twice -> conflict-free b128.
//   P2 r/w: bank = (t&3) + 4*((r&7)^((t>>2)&7)) -> 32 distinct banks per half-wave,
//     2-way across halves -> free (m136).
//   P3 read at F = l+64m+256w, rb = F ^ ((F>>4)&7): (F>>4)&7 = ((l>>4)+4m)&7 is
//     constant per 16-lane group -> residues each twice -> conflict-free b128.
// permlane pair-butterfly (semantics: vdst odd 16/32-lane rows <-> src even rows):
//   swap(x,y): x' = (x_lo, y_lo), y' = (x_hi, y_hi)   [32-lane-half notation]
//   s = x'+y' = (x0+x1, y0+y1), d = x'-y' = (x0-x1, y0-y1)
//   swap(s,d): out0 = (x0+x1, x0-x1) = bfly(x), out1 = (y0+y1, y0-y1) = bfly(y)
//   -> 2 swaps + 2 add/sub butterfly TWO registers; outputs in original positions.

using v4 = __attribute__((ext_vector_type(4))) float;
using u2 = __attribute__((ext_vector_type(2))) unsigned;

__device__ __forceinline__ void bfly_perm32(float& x, float& y) {
    // butterfly across lane-bit 5 (element bit 7), two registers at once
    u2 r = __builtin_amdgcn_permlane32_swap(__float_as_uint(x), __float_as_uint(y),
                                            false, false);
    float u = __uint_as_float(r[0]), v = __uint_as_float(r[1]);
    float s = u + v, d = u - v;
    u2 r2 = __builtin_amdgcn_permlane32_swap(__float_as_uint(s), __float_as_uint(d),
                                             false, false);
    x = __uint_as_float(r2[0]); y = __uint_as_float(r2[1]);
}

__device__ __forceinline__ void bfly_perm16(float& x, float& y) {
    // butterfly across lane-bit 4 (element bit 6), two registers at once
    u2 r = __builtin_amdgcn_permlane16_swap(__float_as_uint(x), __float_as_uint(y),
                                            false, false);
    float u = __uint_as_float(r[0]), v = __uint_as_float(r[1]);
    float s = u + v, d = u - v;
    u2 r2 = __builtin_amdgcn_permlane16_swap(__float_as_uint(s), __float_as_uint(d),
                                             false, false);
    x = __uint_as_float(r2[0]); y = __uint_as_float(r2[1]);
}

__device__ __forceinline__ void had16(float x[16]) {
#pragma unroll
    for (int h = 1; h < 16; h <<= 1) {
#pragma unroll
        for (int i = 0; i < 16; ++i) {
            if (!(i & h)) {
                float a = x[i], b = x[i ^ h];
                x[i] = a + b; x[i ^ h] = a - b;
            }
        }
    }
}

__global__ void __launch_bounds__(256) fwht4096_kernel(const float* __restrict__ in,
                                                       float* __restrict__ out) {
    __shared__ float lds[4096];
    const int t = threadIdx.x;
    const size_t base = (size_t)blockIdx.x * 4096;
    const v4* in4 = reinterpret_cast<const v4*>(in + base);
    v4* out4 = reinterpret_cast<v4*>(out + base);

    // ---------------- P1: bits {0,1,10,11} in regs + {6,7} via permlane ----------------
    v4 v[4];
#pragma unroll
    for (int j = 0; j < 4; ++j) v[j] = __builtin_nontemporal_load(&in4[t + 256 * j]);

#pragma unroll
    for (int j = 0; j < 4; ++j) {  // bits 0,1 (within float4)
        float a = v[j][0], b = v[j][1], c = v[j][2], d = v[j][3];
        float ab = a + b, amb = a - b, cd = c + d, cmd = c - d;
        v[j][0] = ab + cd; v[j][1] = amb + cmd; v[j][2] = ab - cd; v[j][3] = amb - cmd;
    }
    {  // bits 10,11 (across j)
        v4 s0 = v[0] + v[1], d0 = v[0] - v[1];
        v4 s1 = v[2] + v[3], d1 = v[2] - v[3];
        v[0] = s0 + s1; v[2] = s0 - s1;
        v[1] = d0 + d1; v[3] = d0 - d1;
    }
    {  // bits 6,7 via permlane swaps (element bit6 = lane bit4, bit7 = lane bit5)
#pragma unroll
        for (int e = 0; e < 4; ++e) {
            float a0 = v[0][e], a1 = v[1][e], a2 = v[2][e], a3 = v[3][e];
            bfly_perm16(a0, a1); bfly_perm16(a2, a3);
            bfly_perm32(a0, a1); bfly_perm32(a2, a3);
            v[0][e] = a0; v[1][e] = a1; v[2][e] = a2; v[3][e] = a3;
        }
    }
    {  // LDS write at swizzled float4 idx (t ^ ((t>>4)&7)) + 256j
        v4* l4 = reinterpret_cast<v4*>(lds);
        const int wb = t ^ ((t >> 4) & 7);
#pragma unroll
        for (int j = 0; j < 4; ++j) l4[wb + 256 * j] = v[j];
    }
    __syncthreads();

    // ---------------- P2: bits {2..5} ----------------
    // logical elem = (t&3) + 4r + 64*(t>>2); physical = logical with r ^= s2
    {
        float x[16];
        const int b2 = (t & 3) + 64 * (t >> 2);
        const int s2 = (t >> 2) & 7;
#pragma unroll
        for (int r = 0; r < 16; ++r) x[r] = lds[b2 + 4 * (r ^ s2)];
        had16(x);
#pragma unroll
        for (int r = 0; r < 16; ++r) lds[b2 + 4 * (r ^ s2)] = x[r];
    }
    __syncthreads();

    // ---------------- P3: bits {8,9} + gather + vectorized nt-store ----------------
    // thread (w,l) reads float4s at logical f4idx F = l + 64m + 256w (m = 0..3);
    // element bits {9:8} = m -> butterfly across m; store to out4[l + 64m + 256w]
    // (per m, 64 lanes cover a contiguous 1KB segment -> fully coalesced).
    {
        const v4* l4 = reinterpret_cast<const v4*>(lds);
        const int l = t & 63, w = t >> 6;
        v4 g[4];
#pragma unroll
        for (int m = 0; m < 4; ++m) {
            const int F = l + 64 * m + 256 * w;
            const int rb = F ^ ((F >> 4) & 7);
            g[m] = l4[rb];
        }
        v4 s0 = g[0] + g[1], d0 = g[0] - g[1];
        v4 s1 = g[2] + g[3], d1 = g[2] - g[3];
        const float scale = 0.015625f;  // 1/64 = 1/sqrt(4096), exact
        v4 o0 = (s0 + s1) * scale;
        v4 o1 = (d0 + d1) * scale;
        v4 o2 = (s0 - s1) * scale;
        v4 o3 = (d0 - d1) * scale;
        __builtin_nontemporal_store(o0, &out4[l + 256 * w]);
        __builtin_nontemporal_store(o1, &out4[l + 64 + 256 * w]);
        __builtin_nontemporal_store(o2, &out4[l + 128 + 256 * w]);
        __builtin_nontemporal_store(o3, &out4[l + 192 + 256 * w]);
    }
}

extern "C" void kernel_launch(void* const* d_in, const int* in_sizes, int n_in,
                              void* d_out, int out_size, void* d_ws, size_t ws_size,
                              hipStream_t stream) {
    const float* x = (const float*)d_in[0];
    float* out = (float*)d_out;
    const int rows = in_sizes[0] >> 12;  // / 4096
    fwht4096_kernel<<<dim3(rows), dim3(256), 0, stream>>>(x, out);
}